// Round 13
// baseline (170.972 us; speedup 1.0000x reference)
//
#include <hip/hip_runtime.h>

// SAGPool on MI355X, round 13: column-split 256-block pipeline, 4 plain
// launches (kernel boundary = layer sync; no cooperative launch - R11
// killed the container). 2 blocks per graph (64-col halves) x 512 threads.
// Per block: A + X in LDS; W scalar-loaded (R10); phase-2 T in registers via
// readlane (R12). Halves per-CU VALU+LDS vs R12 by using all 256 CUs.
// Evidence: R4 shows graph-replay launch gaps are small; its kernels were
// slow for other reasons (full T re-staging, 4-wave blocks).

#define NGRAPH 128
#define EPG    1024
#define ETOT   131072
#define DIM    128
#define KSEL   32
#define SA     68       // A row stride (floats)
#define SF     132      // X row stride (floats)

// workspace layout (floats)
#define WS_A    0                    // 128*4096 = 524288
#define WS_H1   524288               // 128*64*128 = 1048576 each
#define WS_H2   1572864
#define WS_H3   2621440
#define WS_PREP 3670016              // 2*128*64 = 16384

#define FMA8(A, xs, w0, w1) do { \
  A[0] += (xs)*(w0).x; A[1] += (xs)*(w0).y; A[2] += (xs)*(w0).z; A[3] += (xs)*(w0).w; \
  A[4] += (xs)*(w1).x; A[5] += (xs)*(w1).y; A[6] += (xs)*(w1).z; A[7] += (xs)*(w1).w; } while(0)

__device__ __forceinline__ float rdlane(float v, int lane) {
  return __int_as_float(__builtin_amdgcn_readlane(__float_as_int(v), lane));
}

// ---------------------------------------------------------------------------
// Layer kernel: 256 blocks = (graph g, col-half ch), 512 threads = 8 waves.
// build_adj: build+normalize A from ei (ch==0 also writes wsA); else load wsA.
// T[:,half] = X @ W[:,half] in regs (W scalar);  H = relu(A@T+b) -> Hg;
// preP[ch][g][r] (=|+=) H[r,half].waCol.
// ---------------------------------------------------------------------------
__global__ void __launch_bounds__(512)
k_layer(const float* __restrict__ Xsrc, const int* __restrict__ ei,
        float* __restrict__ wsA, const float* __restrict__ Wg,
        const float* __restrict__ bg, const float* __restrict__ waCol,
        float* __restrict__ Hg, float* __restrict__ preP,
        const int build_adj, const int first)
{
  __shared__ float sA[64 * SA];
  __shared__ float sX[64 * SF];
  __shared__ float ppar[512];
  __shared__ float dv[64];
  const int g   = blockIdx.x >> 1;
  const int ch  = blockIdx.x & 1;
  const int tid = threadIdx.x;

  // ---- adjacency into LDS ----
  if (build_adj) {
    for (int i = tid; i < 64 * SA; i += 512) sA[i] = 0.f;
    __syncthreads();
    {
      const int* srcp = ei + g * EPG;
      const int* dstp = ei + ETOT + g * EPG;
      #pragma unroll
      for (int t = 0; t < 2; ++t) {
        int e = tid + t * 512;
        int s = srcp[e] & 63;
        int d = dstp[e] & 63;
        sA[s * SA + d] = 1.0f;
        sA[d * SA + s] = 1.0f;
      }
    }
    __syncthreads();
    if (tid < 64) sA[tid * SA + tid] += 1.0f;  // +I (self-edge -> 2, as ref)
    __syncthreads();
    if (tid < 256) {
      int r = tid >> 2, q = tid & 3;
      float sum = 0.f;
      int jb = q * 16;
      #pragma unroll
      for (int j = 0; j < 16; ++j) sum += sA[r * SA + jb + j];
      sum += __shfl_xor(sum, 1);
      sum += __shfl_xor(sum, 2);
      if (q == 0) dv[r] = 1.0f / sqrtf(sum);
    }
    __syncthreads();
    for (int i = tid; i < 4096; i += 512) {
      int r = i >> 6, c = i & 63;
      sA[r * SA + c] *= dv[r] * dv[c];
    }
    __syncthreads();
    if (ch == 0) {  // persist normalized A for later kernels
      float* outA = wsA + g * 4096;
      for (int i = tid; i < 4096; i += 512)
        outA[i] = sA[(i >> 6) * SA + (i & 63)];
    }
  } else {
    const float4* asrc = (const float4*)(wsA + g * 4096);
    for (int i = tid; i < 1024; i += 512) {
      int r = i >> 4, c4 = i & 15;
      *(float4*)&sA[r * SA + c4 * 4] = asrc[i];
    }
  }
  { // stage X (x or previous H; same [g*8192 + r*128 + c] layout)
    const float4* s = (const float4*)(Xsrc + g * 8192);
    for (int i = tid; i < 2048; i += 512) {
      int r = i >> 5, q = i & 31;
      *(float4*)&sX[r * SF + q * 4] = s[i];
    }
  }
  __syncthreads();

  const int r  = tid & 63;
  const int w  = tid >> 6;                                   // 0..7
  const int c0 = __builtin_amdgcn_readfirstlane(ch * 64 + w * 8); // uniform col

  // ---- phase 1: acc = T[r, c0..c0+7] = X[r,:] @ W[:,c0..c0+7] ----
  float acc[8] = {0.f,0.f,0.f,0.f,0.f,0.f,0.f,0.f};
  const float* wp = Wg + c0;
  #pragma unroll 4
  for (int kq = 0; kq < 32; ++kq) {
    float4 xv = *(const float4*)&sX[r * SF + kq * 4];        // per-row LDS
    const float* wr = wp + (kq * 4) * DIM;                   // uniform -> s_load
    float4 w00 = *(const float4*)&wr[0];
    float4 w01 = *(const float4*)&wr[4];
    float4 w10 = *(const float4*)&wr[DIM];
    float4 w11 = *(const float4*)&wr[DIM + 4];
    float4 w20 = *(const float4*)&wr[2 * DIM];
    float4 w21 = *(const float4*)&wr[2 * DIM + 4];
    float4 w30 = *(const float4*)&wr[3 * DIM];
    float4 w31 = *(const float4*)&wr[3 * DIM + 4];
    FMA8(acc, xv.x, w00, w01);
    FMA8(acc, xv.y, w10, w11);
    FMA8(acc, xv.z, w20, w21);
    FMA8(acc, xv.w, w30, w31);
  }

  // ---- phase 2: H[r, c0..7] = relu(sum_j A[r,j]*readlane(acc,j) + b) ----
  float4 bv0 = *(const float4*)&bg[c0];
  float4 bv1 = *(const float4*)&bg[c0 + 4];
  float h[8];
  h[0] = bv0.x; h[1] = bv0.y; h[2] = bv0.z; h[3] = bv0.w;
  h[4] = bv1.x; h[5] = bv1.y; h[6] = bv1.z; h[7] = bv1.w;
  for (int jq = 0; jq < 16; ++jq) {
    float4 a4 = *(const float4*)&sA[r * SA + jq * 4];        // per-row LDS
    #pragma unroll
    for (int jj = 0; jj < 4; ++jj) {
      const int lane = jq * 4 + jj;                          // uniform index
      const float aj = (jj == 0) ? a4.x : (jj == 1) ? a4.y
                     : (jj == 2) ? a4.z : a4.w;
      #pragma unroll
      for (int c = 0; c < 8; ++c)
        h[c] += aj * rdlane(acc[c], lane);
    }
  }
  float4 o0, o1;
  o0.x = fmaxf(h[0], 0.f); o0.y = fmaxf(h[1], 0.f);
  o0.z = fmaxf(h[2], 0.f); o0.w = fmaxf(h[3], 0.f);
  o1.x = fmaxf(h[4], 0.f); o1.y = fmaxf(h[5], 0.f);
  o1.z = fmaxf(h[6], 0.f); o1.w = fmaxf(h[7], 0.f);
  *(float4*)&Hg[(g * 64 + r) * DIM + c0]     = o0;           // full-width rows
  *(float4*)&Hg[(g * 64 + r) * DIM + c0 + 4] = o1;
  float4 wa0 = *(const float4*)&waCol[c0];
  float4 wa1 = *(const float4*)&waCol[c0 + 4];
  ppar[w * 64 + r] = o0.x*wa0.x + o0.y*wa0.y + o0.z*wa0.z + o0.w*wa0.w
                   + o1.x*wa1.x + o1.y*wa1.y + o1.z*wa1.z + o1.w*wa1.w;
  __syncthreads();
  if (tid < 64) {
    float s = 0.f;
    #pragma unroll
    for (int q = 0; q < 8; ++q) s += ppar[q * 64 + tid];
    float* pp = preP + (ch * NGRAPH + g) * 64 + tid;
    if (first) *pp = s; else *pp += s;
  }
}

// ---------------------------------------------------------------------------
// Tail kernel: 128 blocks x 256 threads. score/topk/readout/MLP.
// ---------------------------------------------------------------------------
__global__ void __launch_bounds__(256)
k_final(const float* __restrict__ wsA, const float* __restrict__ preP,
        const float* __restrict__ h1g, const float* __restrict__ h2g,
        const float* __restrict__ h3g, const float* __restrict__ ba,
        const float* __restrict__ M1, const float* __restrict__ c1,
        const float* __restrict__ M2, const float* __restrict__ c2,
        const float* __restrict__ M3, const float* __restrict__ c3,
        float* __restrict__ out)
{
  __shared__ float spre[64], ssc[64], ssel[64];
  __shared__ float ro[768], mh[256], hm[128], h2m[64];
  const int g = blockIdx.x, tid = threadIdx.x;

  if (tid < 64)
    spre[tid] = preP[g * 64 + tid] + preP[(NGRAPH + g) * 64 + tid];
  __syncthreads();
  { // score = tanh(A@pre + ba)
    int r = tid >> 2, q = tid & 3;
    const float* Ar = wsA + g * 4096 + r * 64;
    float p = 0.f;
    int jb = q * 16;
    #pragma unroll
    for (int j = 0; j < 16; ++j) p += Ar[jb + j] * spre[jb + j];
    p += __shfl_xor(p, 1);
    p += __shfl_xor(p, 2);
    if (q == 0) ssc[r] = tanhf(p + ba[0]);
  }
  __syncthreads();
  if (tid < 64) { // top-K by rank (value desc, index asc = lax.top_k ties)
    float mys = ssc[tid];
    int cnt = 0;
    for (int j = 0; j < 64; ++j) {
      float sj = ssc[j];
      cnt += (sj > mys || (sj == mys && j < tid)) ? 1 : 0;
    }
    ssel[tid] = (cnt < KSEL) ? 1.0f : 0.0f;
  }
  __syncthreads();
  // readout: mean || max over selected, score-scaled rows
  for (int c = tid; c < 384; c += 256) {
    int which = c >> 7, cc = c & 127;
    const float* hb = ((which == 0) ? h1g : (which == 1) ? h2g : h3g) + g * 8192;
    float sum = 0.f, mx = -1e30f;
    for (int i = 0; i < 64; ++i) {
      if (ssel[i] > 0.5f) {
        float v = ssc[i] * hb[i * DIM + cc];
        sum += v;
        mx = fmaxf(mx, v);
      }
    }
    ro[c]       = sum * (1.0f / KSEL);
    ro[384 + c] = mx;
  }
  __syncthreads();
  // MLP: 768 -> 128 -> 64 -> 10
  {
    int j = tid & 127, half = tid >> 7;
    float a = 0.f;
    int k0 = half * 384;
    for (int k = k0; k < k0 + 384; k += 4) {
      float4 r4 = *(const float4*)&ro[k];
      a += r4.x * M1[(k + 0) * DIM + j];
      a += r4.y * M1[(k + 1) * DIM + j];
      a += r4.z * M1[(k + 2) * DIM + j];
      a += r4.w * M1[(k + 3) * DIM + j];
    }
    mh[half * 128 + j] = a;
  }
  __syncthreads();
  if (tid < 128) hm[tid] = fmaxf(mh[tid] + mh[128 + tid] + c1[tid], 0.f);
  __syncthreads();
  if (tid < 64) {
    float a = c2[tid];
    for (int k = 0; k < 128; ++k) a += hm[k] * M2[k * 64 + tid];
    h2m[tid] = fmaxf(a, 0.f);
  }
  __syncthreads();
  if (tid < 10) {
    float a = c3[tid];
    for (int k = 0; k < 64; ++k) a += h2m[k] * M3[k * 10 + tid];
    out[g * 10 + tid] = a;
  }
}

extern "C" void kernel_launch(void* const* d_in, const int* in_sizes, int n_in,
                              void* d_out, int out_size, void* d_ws, size_t ws_size,
                              hipStream_t stream) {
  const float* x  = (const float*)d_in[0];
  const int*   ei = (const int*)d_in[1];
  // d_in[2] (batch) unused: graphs are contiguous 64-node blocks
  const float* W1 = (const float*)d_in[3];
  const float* b1 = (const float*)d_in[4];
  const float* W2 = (const float*)d_in[5];
  const float* b2 = (const float*)d_in[6];
  const float* W3 = (const float*)d_in[7];
  const float* b3 = (const float*)d_in[8];
  const float* Wa = (const float*)d_in[9];
  const float* ba = (const float*)d_in[10];
  const float* M1 = (const float*)d_in[11];
  const float* c1 = (const float*)d_in[12];
  const float* M2 = (const float*)d_in[13];
  const float* c2 = (const float*)d_in[14];
  const float* M3 = (const float*)d_in[15];
  const float* c3 = (const float*)d_in[16];
  float* out = (float*)d_out;

  float* ws   = (float*)d_ws;
  float* wsA  = ws + WS_A;
  float* h1w  = ws + WS_H1;
  float* h2w  = ws + WS_H2;
  float* h3w  = ws + WS_H3;
  float* preP = ws + WS_PREP;

  k_layer<<<2 * NGRAPH, 512, 0, stream>>>(x,   ei, wsA, W1, b1, Wa,
                                          h1w, preP, 1, 1);
  k_layer<<<2 * NGRAPH, 512, 0, stream>>>(h1w, ei, wsA, W2, b2, Wa + DIM,
                                          h2w, preP, 0, 0);
  k_layer<<<2 * NGRAPH, 512, 0, stream>>>(h2w, ei, wsA, W3, b3, Wa + 2 * DIM,
                                          h3w, preP, 0, 0);
  k_final<<<NGRAPH, 256, 0, stream>>>(wsA, preP, h1w, h2w, h3w, ba,
                                      M1, c1, M2, c2, M3, c3, out);
}

// Round 14
// 144.486 us; speedup vs baseline: 1.1833x; 1.1833x over previous
//
#include <hip/hip_runtime.h>

// SAGPool on MI355X, round 14: single-launch hybrid of the two best designs.
// R10 phase-2 (T in LDS, wave-uniform broadcast reads) + R12 ping-pong
// feature buffers + dedicated T buffer (2 syncs/layer) + unroll-8 on both
// GEMM loops so the compiler batches SMEM/LDS loads and software-pipelines
// them across FMA blocks (the measured wall is latency, not throughput:
// VALUBusy 14-24% across R8/R10/R12 at ~70-75 us).
// Multi-launch abandoned (R2/R4/R13: launch gaps + re-staging lose 2x the
// per-CU gain); cooperative launch banned (R11 killed the container).

#define NGRAPH 128
#define EPG    1024
#define ETOT   131072
#define DIM    128
#define KSEL   32
#define SA     68       // A row stride
#define SF     132      // feature row stride

// LDS layout (floats)
#define O_A    0                     // 64*68  = 4352
#define O_B0   4352                  // 64*132 = 8448 (feature ping)
#define O_B1   12800                 // 64*132 = 8448 (feature pong)
#define O_T    21248                 // 64*132 = 8448 (T scratch)
#define O_PPAR 29696                 // 16*64  = 1024
#define O_PRE  30720                 // 64
#define O_SC   30784                 // 64
#define O_SEL  30848                 // 64
#define LDS_FLOATS 30912
#define LDS_BYTES  (LDS_FLOATS * 4)  // 123648 (< 163840)
// tail scratch aliases T (dead after layer 3):
#define O_RO   O_T                   // 768
#define O_MH   (O_T + 768)           // 1024
#define O_HM   (O_T + 1792)          // 128
#define O_H2M  (O_T + 1920)          // 64

#define FMA8(A, xs, w0, w1) do { \
  A[0] += (xs)*(w0).x; A[1] += (xs)*(w0).y; A[2] += (xs)*(w0).z; A[3] += (xs)*(w0).w; \
  A[4] += (xs)*(w1).x; A[5] += (xs)*(w1).y; A[6] += (xs)*(w1).z; A[7] += (xs)*(w1).w; } while(0)

// One GCN layer. lane r = tid&63 (row), wave w = tid>>6 (col-oct, uniform).
// phase 1: T[r,c0..7] = Bin[r,:] @ W[:,c0..7]   (W via scalar loads)
// phase 2: H[r,c0..7] = relu(A[r,:] @ T[:,c0..7] + b) -> Bout + global Hg;
// pre[r] += H[r,:].waCol via per-wave partials.
__device__ void gcn_layer(float* lds, const float* Bin, float* Bout,
                          const float* __restrict__ Wg,
                          const float* __restrict__ bg,
                          const float* __restrict__ waCol,
                          float* __restrict__ Hg, int tid)
{
  float* sA   = lds + O_A;
  float* sT   = lds + O_T;
  float* ppar = lds + O_PPAR;
  float* pre  = lds + O_PRE;
  const int r  = tid & 63;
  const int w  = tid >> 6;
  const int c0 = __builtin_amdgcn_readfirstlane(w * 8);   // uniform -> s_load

  // ---- phase 1: T = Bin @ W ----
  float acc[8] = {0.f,0.f,0.f,0.f,0.f,0.f,0.f,0.f};
  const float* wp = Wg + c0;
  #pragma unroll 8
  for (int kq = 0; kq < 32; ++kq) {
    float4 xv = *(const float4*)&Bin[r * SF + kq * 4];    // per-row LDS read
    const float* wr = wp + (kq * 4) * DIM;                // uniform -> SGPRs
    float4 w00 = *(const float4*)&wr[0];
    float4 w01 = *(const float4*)&wr[4];
    float4 w10 = *(const float4*)&wr[DIM];
    float4 w11 = *(const float4*)&wr[DIM + 4];
    float4 w20 = *(const float4*)&wr[2 * DIM];
    float4 w21 = *(const float4*)&wr[2 * DIM + 4];
    float4 w30 = *(const float4*)&wr[3 * DIM];
    float4 w31 = *(const float4*)&wr[3 * DIM + 4];
    FMA8(acc, xv.x, w00, w01);
    FMA8(acc, xv.y, w10, w11);
    FMA8(acc, xv.z, w20, w21);
    FMA8(acc, xv.w, w30, w31);
  }
  *(float4*)&sT[r * SF + c0]     = make_float4(acc[0], acc[1], acc[2], acc[3]);
  *(float4*)&sT[r * SF + c0 + 4] = make_float4(acc[4], acc[5], acc[6], acc[7]);
  __syncthreads();                                        // T complete

  // ---- phase 2: H = relu(A @ T + b), T via wave-uniform broadcasts ----
  float4 bv0 = *(const float4*)&bg[c0];
  float4 bv1 = *(const float4*)&bg[c0 + 4];
  float h[8];
  h[0] = bv0.x; h[1] = bv0.y; h[2] = bv0.z; h[3] = bv0.w;
  h[4] = bv1.x; h[5] = bv1.y; h[6] = bv1.z; h[7] = bv1.w;
  #pragma unroll 8
  for (int jq = 0; jq < 16; ++jq) {
    float4 a4 = *(const float4*)&sA[r * SA + jq * 4];     // per-row LDS read
    const float* tb = sT + (jq * 4) * SF + c0;            // uniform -> bcast
    float4 t0, t1;
    t0 = *(const float4*)&tb[0];      t1 = *(const float4*)&tb[4];
    FMA8(h, a4.x, t0, t1);
    t0 = *(const float4*)&tb[SF];     t1 = *(const float4*)&tb[SF + 4];
    FMA8(h, a4.y, t0, t1);
    t0 = *(const float4*)&tb[2 * SF]; t1 = *(const float4*)&tb[2 * SF + 4];
    FMA8(h, a4.z, t0, t1);
    t0 = *(const float4*)&tb[3 * SF]; t1 = *(const float4*)&tb[3 * SF + 4];
    FMA8(h, a4.w, t0, t1);
  }
  float4 o0, o1;
  o0.x = fmaxf(h[0], 0.f); o0.y = fmaxf(h[1], 0.f);
  o0.z = fmaxf(h[2], 0.f); o0.w = fmaxf(h[3], 0.f);
  o1.x = fmaxf(h[4], 0.f); o1.y = fmaxf(h[5], 0.f);
  o1.z = fmaxf(h[6], 0.f); o1.w = fmaxf(h[7], 0.f);
  *(float4*)&Bout[r * SF + c0]     = o0;                  // ping-pong, no race
  *(float4*)&Bout[r * SF + c0 + 4] = o1;
  *(float4*)&Hg[r * DIM + c0]      = o0;                  // for tail readout
  *(float4*)&Hg[r * DIM + c0 + 4]  = o1;
  float4 wa0 = *(const float4*)&waCol[c0];
  float4 wa1 = *(const float4*)&waCol[c0 + 4];
  ppar[w * 64 + r] = o0.x*wa0.x + o0.y*wa0.y + o0.z*wa0.z + o0.w*wa0.w
                   + o1.x*wa1.x + o1.y*wa1.y + o1.z*wa1.z + o1.w*wa1.w;
  __syncthreads();                 // Bout + ppar complete; T reads done
  if (tid < 64) {
    float s = 0.f;
    #pragma unroll
    for (int q = 0; q < 16; ++q) s += ppar[q * 64 + tid];
    pre[tid] += s;
  }
  // next ppar write is after next layer's first sync; reduce is ordered
  // before this thread re-enters that sync. safe without extra barrier.
}

extern "C" __global__ void __launch_bounds__(1024)
sagpool(const float* __restrict__ x,  const int* __restrict__ ei,
        const float* __restrict__ W1, const float* __restrict__ b1,
        const float* __restrict__ W2, const float* __restrict__ b2,
        const float* __restrict__ W3, const float* __restrict__ b3,
        const float* __restrict__ Wa, const float* __restrict__ ba,
        const float* __restrict__ M1, const float* __restrict__ c1,
        const float* __restrict__ M2, const float* __restrict__ c2,
        const float* __restrict__ M3, const float* __restrict__ c3,
        float* __restrict__ h1w, float* __restrict__ h2w,
        float* __restrict__ h3w, float* __restrict__ out)
{
  extern __shared__ float lds[];
  const int g = blockIdx.x, tid = threadIdx.x;
  float* sA  = lds + O_A;
  float* B0  = lds + O_B0;
  float* B1  = lds + O_B1;
  float* pre = lds + O_PRE;
  float* sc  = lds + O_SC;   // dinv, later score
  float* sel = lds + O_SEL;
  float* ro  = lds + O_RO;
  float* mh  = lds + O_MH;
  float* hm  = lds + O_HM;
  float* h2m = lds + O_H2M;

  // ---- adjacency: build, +I, D^-1/2 normalize ----
  for (int i = tid; i < 64 * SA; i += 1024) sA[i] = 0.f;
  if (tid < 64) pre[tid] = 0.f;
  __syncthreads();
  {
    int s = ei[g * EPG + tid] & 63;           // EPG == blockDim.x
    int d = ei[ETOT + g * EPG + tid] & 63;
    sA[s * SA + d] = 1.0f;
    sA[d * SA + s] = 1.0f;
  }
  __syncthreads();
  if (tid < 64) sA[tid * SA + tid] += 1.0f;   // +I (self-edge -> 2, matches ref)
  __syncthreads();
  {
    int r = tid >> 4, q = tid & 15;
    float sum = sA[r * SA + q * 4]     + sA[r * SA + q * 4 + 1]
              + sA[r * SA + q * 4 + 2] + sA[r * SA + q * 4 + 3];
    sum += __shfl_xor(sum, 1);
    sum += __shfl_xor(sum, 2);
    sum += __shfl_xor(sum, 4);
    sum += __shfl_xor(sum, 8);
    if (q == 0) sc[r] = 1.0f / sqrtf(sum);
  }
  __syncthreads();
  for (int i = tid; i < 4096; i += 1024) {
    int r = i >> 6, c = i & 63;
    sA[r * SA + c] *= sc[r] * sc[c];
  }
  { // stage x into B0 [64][132]
    const float4* xg = (const float4*)(x + g * 64 * DIM);
    for (int i = tid; i < 2048; i += 1024) {
      int r = i >> 5, q = i & 31;
      *(float4*)&B0[r * SF + q * 4] = xg[i];
    }
  }
  __syncthreads();

  // ---- 3 GCN layers (B0 -> B1 -> B0 -> B1) ----
  gcn_layer(lds, B0, B1, W1, b1, Wa,           h1w + g * 8192, tid);
  gcn_layer(lds, B1, B0, W2, b2, Wa + DIM,     h2w + g * 8192, tid);
  gcn_layer(lds, B0, B1, W3, b3, Wa + 2 * DIM, h3w + g * 8192, tid);
  __syncthreads();                 // pre complete; T region free for tail

  // ---- score = tanh(A @ pre + ba) ----
  {
    int r = tid >> 4, q = tid & 15;
    float p = sA[r * SA + q * 4]     * pre[q * 4]
            + sA[r * SA + q * 4 + 1] * pre[q * 4 + 1]
            + sA[r * SA + q * 4 + 2] * pre[q * 4 + 2]
            + sA[r * SA + q * 4 + 3] * pre[q * 4 + 3];
    p += __shfl_xor(p, 1);
    p += __shfl_xor(p, 2);
    p += __shfl_xor(p, 4);
    p += __shfl_xor(p, 8);
    if (q == 0) sc[r] = tanhf(p + ba[0]);
  }
  __syncthreads();

  // ---- top-K by rank (value desc, index asc = lax.top_k tie order) ----
  if (tid < 64) {
    float mys = sc[tid];
    int cnt = 0;
    for (int j = 0; j < 64; ++j) {
      float sj = sc[j];
      cnt += (sj > mys || (sj == mys && j < tid)) ? 1 : 0;
    }
    sel[tid] = (cnt < KSEL) ? 1.0f : 0.0f;
  }
  __syncthreads();

  // ---- readout: mean || max of score-scaled selected rows (H from global) ----
  if (tid < 768) {
    int c = tid >> 1, half = tid & 1;          // c in 0..383
    int which = c >> 7, cc = c & 127;
    const float* hb = ((which == 0) ? h1w : (which == 1) ? h2w : h3w) + g * 8192;
    float sum = 0.f, mx = -1e30f;
    for (int i = half * 32; i < half * 32 + 32; ++i) {
      if (sel[i] > 0.5f) {
        float v = sc[i] * hb[i * DIM + cc];
        sum += v;
        mx = fmaxf(mx, v);
      }
    }
    sum += __shfl_xor(sum, 1);
    mx = fmaxf(mx, __shfl_xor(mx, 1));
    if (half == 0) {
      ro[c]       = sum * (1.0f / KSEL);
      ro[384 + c] = mx;
    }
  }
  __syncthreads();

  // ---- MLP: 768 -> 128 -> 64 -> 10 ----
  {
    int j = tid & 127, oc = tid >> 7;          // 8 k-chunks of 96
    float a = 0.f;
    int k0 = oc * 96;
    for (int k = k0; k < k0 + 96; k += 4) {
      float4 r4 = *(const float4*)&ro[k];
      a += r4.x * M1[(k + 0) * DIM + j];
      a += r4.y * M1[(k + 1) * DIM + j];
      a += r4.z * M1[(k + 2) * DIM + j];
      a += r4.w * M1[(k + 3) * DIM + j];
    }
    mh[oc * 128 + j] = a;
  }
  __syncthreads();
  if (tid < 128) {
    float v = c1[tid];
    #pragma unroll
    for (int q = 0; q < 8; ++q) v += mh[q * 128 + tid];
    hm[tid] = fmaxf(v, 0.f);
  }
  __syncthreads();
  if (tid < 64) {
    float a = c2[tid];
    for (int k = 0; k < 128; ++k) a += hm[k] * M2[k * 64 + tid];
    h2m[tid] = fmaxf(a, 0.f);
  }
  __syncthreads();
  if (tid < 10) {
    float a = c3[tid];
    for (int k = 0; k < 64; ++k) a += h2m[k] * M3[k * 10 + tid];
    out[g * 10 + tid] = a;
  }
}

extern "C" void kernel_launch(void* const* d_in, const int* in_sizes, int n_in,
                              void* d_out, int out_size, void* d_ws, size_t ws_size,
                              hipStream_t stream) {
  const float* x  = (const float*)d_in[0];
  const int*   ei = (const int*)d_in[1];
  // d_in[2] (batch) unused: graphs are contiguous 64-node blocks
  const float* W1 = (const float*)d_in[3];
  const float* b1 = (const float*)d_in[4];
  const float* W2 = (const float*)d_in[5];
  const float* b2 = (const float*)d_in[6];
  const float* W3 = (const float*)d_in[7];
  const float* b3 = (const float*)d_in[8];
  const float* Wa = (const float*)d_in[9];
  const float* ba = (const float*)d_in[10];
  const float* M1 = (const float*)d_in[11];
  const float* c1 = (const float*)d_in[12];
  const float* M2 = (const float*)d_in[13];
  const float* c2 = (const float*)d_in[14];
  const float* M3 = (const float*)d_in[15];
  const float* c3 = (const float*)d_in[16];
  float* out = (float*)d_out;

  float* ws  = (float*)d_ws;
  float* h1w = ws;                    // 128*64*128 = 1M floats each
  float* h2w = ws + 1048576;
  float* h3w = ws + 2097152;

  (void)hipFuncSetAttribute(reinterpret_cast<const void*>(sagpool),
                            hipFuncAttributeMaxDynamicSharedMemorySize, LDS_BYTES);
  sagpool<<<NGRAPH, 1024, LDS_BYTES, stream>>>(x, ei, W1, b1, W2, b2, W3, b3,
                                               Wa, ba, M1, c1, M2, c2, M3, c3,
                                               h1w, h2w, h3w, out);
}